// Round 1
// baseline (36.545 us; speedup 1.0000x reference)
//
#include <hip/hip_runtime.h>
#include <math.h>

#define D_IN  2048
#define D_OUT 8192

// XOR swizzles (involutions, affect bits 2-4 only) for bank-conflict-free LDS.
__device__ __forceinline__ int swz3(int i) { return i ^ (((i >> 5) & 7) << 2); }  // 32-float-stride regions
__device__ __forceinline__ int swz1(int i) { return i ^ (((i >> 5) & 1) << 2); }  // 8-float-stride regions

__global__ __launch_bounds__(256) void fastfood_kernel(
    const float* __restrict__ xg, const float* __restrict__ Bg,
    const float* __restrict__ Gg, const float* __restrict__ Sg,
    const int*   __restrict__ Pg, const float* __restrict__ Ug,
    float* __restrict__ outg)
{
  __shared__ float4 a4[D_IN / 4];   // 8 KB: FWHT-2048 result (swz1 layout)
  __shared__ float4 b4[D_OUT / 4];  // 32 KB: transpose scratch (swz3 layout; swz1 during exchange)
  float* a_lds = reinterpret_cast<float*>(a4);
  float* b_lds = reinterpret_cast<float*>(b4);

  const int t    = threadIdx.x;   // 0..255
  const int lane = t & 63;
  const int wave = t >> 6;
  const int row  = blockIdx.x;

  // ================= FWHT-2048 of B*x =================
  // layout: a8[k] = A[t*8 + k]  (global bits 0-2 = k, 3-8 = lane, 9-10 = wave)
  float a8[8];
  {
    const float4* x4  = reinterpret_cast<const float4*>(xg + (size_t)row * D_IN);
    const float4* B4p = reinterpret_cast<const float4*>(Bg);
    float4 xa = x4[2 * t], xb = x4[2 * t + 1];
    float4 ba = B4p[2 * t], bb = B4p[2 * t + 1];
    a8[0] = xa.x * ba.x; a8[1] = xa.y * ba.y; a8[2] = xa.z * ba.z; a8[3] = xa.w * ba.w;
    a8[4] = xb.x * bb.x; a8[5] = xb.y * bb.y; a8[6] = xb.z * bb.z; a8[7] = xb.w * bb.w;
  }
  // stages h = 1,2,4 (in-register)
  #pragma unroll
  for (int h = 1; h <= 4; h <<= 1) {
    #pragma unroll
    for (int i = 0; i < 8; ++i) {
      if (!(i & h)) { float lo = a8[i], hi = a8[i | h]; a8[i] = lo + hi; a8[i | h] = lo - hi; }
    }
  }
  // stages h = 8..256 (lane xor masks 1..32)
  #pragma unroll
  for (int m = 1; m <= 32; m <<= 1) {
    float sgn = (lane & m) ? -1.0f : 1.0f;
    #pragma unroll
    for (int k = 0; k < 8; ++k) {
      float p = __shfl_xor(a8[k], m, 64);
      a8[k] = fmaf(sgn, a8[k], p);  // bit set: p - v ; clear: v + p  (exact)
    }
  }
  // stages h = 512,1024: 4-way cross-wave combine via LDS (scratch = b_lds, swz1)
  {
    float4* sc = reinterpret_cast<float4*>(b_lds);
    int base = t * 8;
    sc[swz1(base) >> 2]     = make_float4(a8[0], a8[1], a8[2], a8[3]);
    sc[swz1(base + 4) >> 2] = make_float4(a8[4], a8[5], a8[6], a8[7]);
    __syncthreads();
    float pw[4][8];
    #pragma unroll
    for (int w = 0; w < 4; ++w) {
      int pb = (w * 64 + lane) * 8;
      float4 v0 = sc[swz1(pb) >> 2];
      float4 v1 = sc[swz1(pb + 4) >> 2];
      pw[w][0] = v0.x; pw[w][1] = v0.y; pw[w][2] = v0.z; pw[w][3] = v0.w;
      pw[w][4] = v1.x; pw[w][5] = v1.y; pw[w][6] = v1.z; pw[w][7] = v1.w;
    }
    float s0 = (wave & 1) ? -1.0f : 1.0f;
    float s1 = (wave & 2) ? -1.0f : 1.0f;
    #pragma unroll
    for (int k = 0; k < 8; ++k) {
      // matches sequential stages: (in0 +- in1) +- (in2 +- in3)
      float u01 = fmaf(s0, pw[1][k], pw[0][k]);
      float u23 = fmaf(s0, pw[3][k], pw[2][k]);
      a8[k] = fmaf(s1, u23, u01);
    }
  }
  // store FWHT-2048 result for the random gather
  {
    float4* av = reinterpret_cast<float4*>(a_lds);
    int base = t * 8;
    av[swz1(base) >> 2]     = make_float4(a8[0], a8[1], a8[2], a8[3]);
    av[swz1(base + 4) >> 2] = make_float4(a8[4], a8[5], a8[6], a8[7]);
  }
  __syncthreads();

  // ================= gather + FWHT-8192 =================
  // phase A layout: v[k] = b[t*32 + k]  (bits 0-4 in-register)
  float v[32];
  {
    const int4*   P4 = reinterpret_cast<const int4*>(Pg);
    const float4* G4 = reinterpret_cast<const float4*>(Gg);
    #pragma unroll
    for (int g = 0; g < 8; ++g) {
      int4   pp = P4[t * 8 + g];
      float4 gv = G4[t * 8 + g];
      v[4 * g + 0] = a_lds[swz1(pp.x & (D_IN - 1))] * gv.x;
      v[4 * g + 1] = a_lds[swz1(pp.y & (D_IN - 1))] * gv.y;
      v[4 * g + 2] = a_lds[swz1(pp.z & (D_IN - 1))] * gv.z;
      v[4 * g + 3] = a_lds[swz1(pp.w & (D_IN - 1))] * gv.w;
    }
  }
  // phase A: h = 1..16
  #pragma unroll
  for (int h = 1; h <= 16; h <<= 1) {
    #pragma unroll
    for (int i = 0; i < 32; ++i) {
      if (!(i & h)) { float lo = v[i], hi = v[i | h]; v[i] = lo + hi; v[i | h] = lo - hi; }
    }
  }
  // A->B transpose (write contiguous b128, swz3)
  {
    float4* bv = reinterpret_cast<float4*>(b_lds);
    #pragma unroll
    for (int g = 0; g < 8; ++g) {
      int w = t * 32 + 4 * g;
      bv[swz3(w) >> 2] = make_float4(v[4 * g], v[4 * g + 1], v[4 * g + 2], v[4 * g + 3]);
    }
  }
  __syncthreads();
  // phase B layout: u[k] = b[hi*1024 + k*32 + lo]  (bits 5-9 in-register)
  float u[32];
  {
    const int hi = t >> 5, lo = t & 31;
    #pragma unroll
    for (int k = 0; k < 32; ++k)
      u[k] = b_lds[swz3(hi * 1024 + k * 32 + lo)];
  }
  // phase B: h = 32..512
  #pragma unroll
  for (int h = 1; h <= 16; h <<= 1) {
    #pragma unroll
    for (int i = 0; i < 32; ++i) {
      if (!(i & h)) { float lo = u[i], hi = u[i | h]; u[i] = lo + hi; u[i | h] = lo - hi; }
    }
  }
  __syncthreads();  // all phase-B reads complete before overwrite
  {
    const int hi = t >> 5, lo = t & 31;
    #pragma unroll
    for (int k = 0; k < 32; ++k)
      b_lds[swz3(hi * 1024 + k * 32 + lo)] = u[k];
  }
  __syncthreads();
  // phase C layout: c[m][j] = b[j*1024 + m*256 + t]  (bits 10-12 = j in-register)
  float c[4][8];
  #pragma unroll
  for (int m = 0; m < 4; ++m) {
    #pragma unroll
    for (int j = 0; j < 8; ++j)
      c[m][j] = b_lds[swz3(j * 1024 + m * 256 + t)];
  }
  // phase C: h = 1024,2048,4096 (j bits 0-2)
  #pragma unroll
  for (int h = 1; h <= 4; h <<= 1) {
    #pragma unroll
    for (int m = 0; m < 4; ++m) {
      #pragma unroll
      for (int j = 0; j < 8; ++j) {
        if (!(j & h)) { float lo = c[m][j], hi = c[m][j | h]; c[m][j] = lo + hi; c[m][j | h] = lo - hi; }
      }
    }
  }

  // ================= epilogue: cos(Vx + 2*pi*U) * sqrt(2/O) =================
  {
    const float c1 = (float)(1.0 / (6.283185307179586 * 90.50966799187809)); // 1/(2*pi*sqrt(8192))
    float* outr = outg + (size_t)row * D_OUT;
    #pragma unroll
    for (int m = 0; m < 4; ++m) {
      #pragma unroll
      for (int j = 0; j < 8; ++j) {
        int o = j * 1024 + m * 256 + t;
        float rev = fmaf(c[m][j] * Sg[o], c1, Ug[o]);   // revolutions: Vx/(2pi) + U
        float r = rev - rintf(rev);                     // [-0.5, 0.5]
        outr[o] = __builtin_amdgcn_cosf(r) * 0.015625f; // cos(2*pi*r) * sqrt(2/8192)
      }
    }
  }
}

extern "C" void kernel_launch(void* const* d_in, const int* in_sizes, int n_in,
                              void* d_out, int out_size, void* d_ws, size_t ws_size,
                              hipStream_t stream) {
  const float* x = (const float*)d_in[0];
  const float* B = (const float*)d_in[1];
  const float* G = (const float*)d_in[2];
  const float* S = (const float*)d_in[3];
  const int*   P = (const int*)d_in[4];
  const float* U = (const float*)d_in[5];
  float* out = (float*)d_out;
  const int rows = in_sizes[0] / D_IN;  // 2048
  fastfood_kernel<<<rows, 256, 0, stream>>>(x, B, G, S, P, U, out);
}